// Round 1
// baseline (4381.101 us; speedup 1.0000x reference)
//
#include <hip/hip_runtime.h>

#define B_   4
#define S_   4096
#define Hd   2048
#define NHh  16
#define HDd  128
#define FDd  64
#define MTOT (B_*S_)      // 16384
#define JD   (NHh*FDd)    // 1024

// ---------------------------------------------------------------------------
// Combine weights: Wc[h*64+f, i] = sum_d Wf[f,d] * W[h*128+d, i]
//                  bc[h*64+f]    = sum_d  b[h*128+d] * Wf[f,d]
// grid: (8 i-chunks of 256, 16 h, 2 which)   block: 256
// ---------------------------------------------------------------------------
__global__ __launch_bounds__(256) void combine_w_kernel(
    const float* __restrict__ Wq, const float* __restrict__ Wqf, const float* __restrict__ bq,
    const float* __restrict__ Wk, const float* __restrict__ Wkf, const float* __restrict__ bk,
    float* __restrict__ Wcq, float* __restrict__ bcq,
    float* __restrict__ Wck, float* __restrict__ bck)
{
    const int tid = threadIdx.x;
    const int h = blockIdx.y;
    const int which = blockIdx.z;
    const float* W  = which ? Wk  : Wq;
    const float* Wf = which ? Wkf : Wqf;
    const float* bb = which ? bk  : bq;
    float* Wc = which ? Wck : Wcq;
    float* bc = which ? bck : bcq;

    __shared__ float wfT[128 * 64];   // [d][f]
    for (int idx = tid; idx < 64 * 128; idx += 256) {
        int f = idx >> 7, d = idx & 127;
        wfT[d * 64 + f] = Wf[idx];
    }
    __syncthreads();

    const int i = blockIdx.x * 256 + tid;
    float acc[64];
#pragma unroll
    for (int f = 0; f < 64; f++) acc[f] = 0.f;

    for (int d = 0; d < 128; d++) {
        float w = W[(size_t)(h * 128 + d) * Hd + i];
        const float* wr = &wfT[d * 64];
#pragma unroll
        for (int f4 = 0; f4 < 16; f4++) {
            float4 ww = *(const float4*)&wr[f4 * 4];
            acc[f4 * 4 + 0] += ww.x * w;
            acc[f4 * 4 + 1] += ww.y * w;
            acc[f4 * 4 + 2] += ww.z * w;
            acc[f4 * 4 + 3] += ww.w * w;
        }
    }
#pragma unroll
    for (int f = 0; f < 64; f++)
        Wc[(size_t)(h * 64 + f) * Hd + i] = acc[f];

    if (blockIdx.x == 0 && tid < 64) {
        float s = 0.f;
        for (int d = 0; d < 128; d++) s += bb[h * 128 + d] * wfT[d * 64 + tid];
        bc[h * 64 + tid] = s;
    }
}

// ---------------------------------------------------------------------------
// SGEMM NT: C[m,n] = epi( sum_k A[m,k]*B[n,k] + bias[n] )
// MODE 0: +bias      MODE 1: relu(+bias)      MODE 2: relu(+bias)*mask[m]
// 128x128 tile, BK=16, 256 threads, 8x8 per thread (4+4 split)
// ---------------------------------------------------------------------------
template <int MODE>
__global__ __launch_bounds__(256) void gemm_nt(
    const float* __restrict__ A, const float* __restrict__ Bm,
    const float* __restrict__ bias, const float* __restrict__ mask,
    float* __restrict__ C, int N, int K)
{
    __shared__ float As[16][132];
    __shared__ float Bs[16][132];
    const int tid = threadIdx.x;
    const int bm = blockIdx.y * 128;
    const int bn = blockIdx.x * 128;
    const int tx = tid & 15, ty = tid >> 4;
    const int lrow = tid >> 2;          // 0..63
    const int lcol = (tid & 3) << 2;    // 0,4,8,12

    float accf[8][8];
#pragma unroll
    for (int i = 0; i < 8; i++)
#pragma unroll
        for (int j = 0; j < 8; j++) accf[i][j] = 0.f;

    const float* Ap  = A  + (size_t)(bm + lrow) * K + lcol;
    const float* Ap2 = Ap + (size_t)64 * K;
    const float* Bp  = Bm + (size_t)(bn + lrow) * K + lcol;
    const float* Bp2 = Bp + (size_t)64 * K;

    for (int k0 = 0; k0 < K; k0 += 16) {
        float4 a0 = *(const float4*)(Ap  + k0);
        float4 a1 = *(const float4*)(Ap2 + k0);
        float4 b0 = *(const float4*)(Bp  + k0);
        float4 b1 = *(const float4*)(Bp2 + k0);
        __syncthreads();
        As[lcol + 0][lrow] = a0.x; As[lcol + 1][lrow] = a0.y;
        As[lcol + 2][lrow] = a0.z; As[lcol + 3][lrow] = a0.w;
        As[lcol + 0][lrow + 64] = a1.x; As[lcol + 1][lrow + 64] = a1.y;
        As[lcol + 2][lrow + 64] = a1.z; As[lcol + 3][lrow + 64] = a1.w;
        Bs[lcol + 0][lrow] = b0.x; Bs[lcol + 1][lrow] = b0.y;
        Bs[lcol + 2][lrow] = b0.z; Bs[lcol + 3][lrow] = b0.w;
        Bs[lcol + 0][lrow + 64] = b1.x; Bs[lcol + 1][lrow + 64] = b1.y;
        Bs[lcol + 2][lrow + 64] = b1.z; Bs[lcol + 3][lrow + 64] = b1.w;
        __syncthreads();
#pragma unroll
        for (int kk = 0; kk < 16; kk++) {
            const float4 av0 = *(const float4*)&As[kk][ty * 4];
            const float4 av1 = *(const float4*)&As[kk][ty * 4 + 64];
            const float4 bv0 = *(const float4*)&Bs[kk][tx * 4];
            const float4 bv1 = *(const float4*)&Bs[kk][tx * 4 + 64];
            const float a_[8] = {av0.x, av0.y, av0.z, av0.w, av1.x, av1.y, av1.z, av1.w};
            const float b_[8] = {bv0.x, bv0.y, bv0.z, bv0.w, bv1.x, bv1.y, bv1.z, bv1.w};
#pragma unroll
            for (int i = 0; i < 8; i++)
#pragma unroll
                for (int j = 0; j < 8; j++)
                    accf[i][j] += a_[i] * b_[j];
        }
    }

#pragma unroll
    for (int i = 0; i < 8; i++) {
        int row = bm + (i >> 2) * 64 + ty * 4 + (i & 3);
        float mval = (MODE == 2) ? mask[row] : 1.f;
#pragma unroll
        for (int jh = 0; jh < 2; jh++) {
            int col = bn + jh * 64 + tx * 4;
            float4 bv4 = *(const float4*)&bias[col];
            float4 r;
            r.x = accf[i][jh * 4 + 0] + bv4.x;
            r.y = accf[i][jh * 4 + 1] + bv4.y;
            r.z = accf[i][jh * 4 + 2] + bv4.z;
            r.w = accf[i][jh * 4 + 3] + bv4.w;
            if (MODE >= 1) {
                r.x = r.x > 0.f ? r.x : 0.f;
                r.y = r.y > 0.f ? r.y : 0.f;
                r.z = r.z > 0.f ? r.z : 0.f;
                r.w = r.w > 0.f ? r.w : 0.f;
            }
            if (MODE == 2) { r.x *= mval; r.y *= mval; r.z *= mval; r.w *= mval; }
            *(float4*)&C[(size_t)row * N + col] = r;
        }
    }
}

// ---------------------------------------------------------------------------
// kv partial: per (b,h,chunk) accumulate kv[f,e] += k'[n,f]*v[n,e], ksum[f]
// grid: (8 chunks, 64 bh)  block 256; thread: f = (tid&15)*4..+3, e = (tid>>4)*8..+7
// ---------------------------------------------------------------------------
__global__ __launch_bounds__(256) void kv_partial_kernel(
    const float* __restrict__ kp, const float* __restrict__ v,
    float* __restrict__ kv_part, float* __restrict__ ksum_part)
{
    const int tid = threadIdx.x;
    const int bh = blockIdx.y;
    const int b = bh >> 4, h = bh & 15;
    const int c = blockIdx.x;
    __shared__ float Ks[8][64];
    __shared__ float Vs[8][128];
    const int fi = tid & 15;
    const int eg = tid >> 4;
    float acc[4][8];
#pragma unroll
    for (int i = 0; i < 4; i++)
#pragma unroll
        for (int j = 0; j < 8; j++) acc[i][j] = 0.f;
    float ksacc = 0.f;

    for (int n0 = c * 512; n0 < c * 512 + 512; n0 += 8) {
        __syncthreads();
        if (tid < 128) {
            int nn = tid >> 4, fc = (tid & 15) << 2;
            *(float4*)&Ks[nn][fc] = *(const float4*)&kp[(size_t)(b * S_ + n0 + nn) * JD + h * 64 + fc];
        }
        {
            int nn = tid >> 5, ec = (tid & 31) << 2;
            *(float4*)&Vs[nn][ec] = *(const float4*)&v[(size_t)(b * S_ + n0 + nn) * Hd + h * 128 + ec];
        }
        __syncthreads();
#pragma unroll
        for (int nn = 0; nn < 8; nn++) {
            float4 kk = *(const float4*)&Ks[nn][fi * 4];
            float4 v0 = *(const float4*)&Vs[nn][eg * 8];
            float4 v1 = *(const float4*)&Vs[nn][eg * 8 + 4];
            const float kf[4] = {kk.x, kk.y, kk.z, kk.w};
            const float vf[8] = {v0.x, v0.y, v0.z, v0.w, v1.x, v1.y, v1.z, v1.w};
#pragma unroll
            for (int i = 0; i < 4; i++)
#pragma unroll
                for (int j = 0; j < 8; j++) acc[i][j] += kf[i] * vf[j];
            if (tid < 64) ksacc += Ks[nn][tid];
        }
    }
    size_t base = ((size_t)c * 64 + bh) * 8192;
#pragma unroll
    for (int i = 0; i < 4; i++) {
        int f = fi * 4 + i;
        float4 r0 = {acc[i][0], acc[i][1], acc[i][2], acc[i][3]};
        float4 r1 = {acc[i][4], acc[i][5], acc[i][6], acc[i][7]};
        *(float4*)&kv_part[base + (size_t)f * 128 + eg * 8]     = r0;
        *(float4*)&kv_part[base + (size_t)f * 128 + eg * 8 + 4] = r1;
    }
    if (tid < 64) ksum_part[((size_t)c * 64 + bh) * 64 + tid] = ksacc;
}

__global__ __launch_bounds__(256) void kv_reduce_kernel(
    const float* __restrict__ kv_part, const float* __restrict__ ksum_part,
    float* __restrict__ kv, float* __restrict__ ksum)
{
    const int bh = blockIdx.x, tid = threadIdx.x;
    for (int idx = tid; idx < 8192; idx += 256) {
        float s = 0.f;
#pragma unroll
        for (int c = 0; c < 8; c++) s += kv_part[((size_t)c * 64 + bh) * 8192 + idx];
        kv[(size_t)bh * 8192 + idx] = s;
    }
    if (tid < 64) {
        float s = 0.f;
#pragma unroll
        for (int c = 0; c < 8; c++) s += ksum_part[((size_t)c * 64 + bh) * 64 + tid];
        ksum[bh * 64 + tid] = s;
    }
}

// ---------------------------------------------------------------------------
// rscale[b,h,n] = 1 / (sum_f q'[m, h*64+f]*ksum[b,h,f] + 1e-8)
// ---------------------------------------------------------------------------
__global__ __launch_bounds__(256) void rscale_kernel(
    const float* __restrict__ qp, const float* __restrict__ ksum, float* __restrict__ rscale)
{
    int idx = blockIdx.x * 256 + threadIdx.x;   // 0..262143
    int m = idx >> 4;
    int h = idx & 15;
    int b = m >> 12;
    int n = m & 4095;
    const float* q  = qp + (size_t)m * JD + h * 64;
    const float* ks = ksum + (b * 16 + h) * 64;
    float s = 0.f;
#pragma unroll
    for (int f4 = 0; f4 < 16; f4++) {
        float4 qa = *(const float4*)&q[f4 * 4];
        float4 ka = *(const float4*)&ks[f4 * 4];
        s += qa.x * ka.x + qa.y * ka.y + qa.z * ka.z + qa.w * ka.w;
    }
    rscale[(size_t)(b * 16 + h) * S_ + n] = 1.f / (s + 1e-8f);
}

// ---------------------------------------------------------------------------
// kvo[b, h*64+f, o] = sum_e kv[b,h,f,e] * Wo[o, h*128+e]
// grid: (8 o-chunks of 256, 64 bh)  block 256
// ---------------------------------------------------------------------------
__global__ __launch_bounds__(256) void kvo_kernel(
    const float* __restrict__ kv, const float* __restrict__ Wo, float* __restrict__ kvo)
{
    const int tid = threadIdx.x;
    const int bh = blockIdx.y;
    const int b = bh >> 4, h = bh & 15;
    const int o0 = blockIdx.x * 256;
    __shared__ float kvs[8192];
    for (int idx = tid * 4; idx < 8192; idx += 1024)
        *(float4*)&kvs[idx] = *(const float4*)&kv[(size_t)bh * 8192 + idx];
    __syncthreads();

    const int ol = tid & 63;
    const int fg = tid >> 6;   // 0..3 -> f = fg*16..+15
    float acc[4][16];
#pragma unroll
    for (int i = 0; i < 4; i++)
#pragma unroll
        for (int j = 0; j < 16; j++) acc[i][j] = 0.f;

    for (int e4 = 0; e4 < 32; e4++) {
        float4 wv[4];
#pragma unroll
        for (int oo = 0; oo < 4; oo++) {
            int o = o0 + oo * 64 + ol;
            wv[oo] = *(const float4*)&Wo[(size_t)o * Hd + h * 128 + e4 * 4];
        }
#pragma unroll
        for (int ff = 0; ff < 16; ff++) {
            float4 kk = *(const float4*)&kvs[(fg * 16 + ff) * 128 + e4 * 4];
#pragma unroll
            for (int oo = 0; oo < 4; oo++)
                acc[oo][ff] += kk.x * wv[oo].x + kk.y * wv[oo].y + kk.z * wv[oo].z + kk.w * wv[oo].w;
        }
    }
#pragma unroll
    for (int ff = 0; ff < 16; ff++) {
        int f = fg * 16 + ff;
#pragma unroll
        for (int oo = 0; oo < 4; oo++)
            kvo[((size_t)b * 1024 + h * 64 + f) * Hd + o0 + oo * 64 + ol] = acc[oo][ff];
    }
}

// ---------------------------------------------------------------------------
// Final: out[b*4096+m, o] = sum_j (q'[m,j]*rscale[b, j/64, m]) * kvo[b,j,o] + bo[o]
// NN GEMM per b, K=1024, 128x128 tile
// ---------------------------------------------------------------------------
__global__ __launch_bounds__(256) void gemm_out_kernel(
    const float* __restrict__ qp, const float* __restrict__ rscale,
    const float* __restrict__ kvo, const float* __restrict__ bo,
    float* __restrict__ out)
{
    const int b = blockIdx.z;
    const int bm = blockIdx.y * 128;   // within b
    const int bn = blockIdx.x * 128;
    __shared__ float As[16][132];
    __shared__ float Bs[16][132];
    const int tid = threadIdx.x;
    const int tx = tid & 15, ty = tid >> 4;
    const int lrow = tid >> 2;
    const int lcol = (tid & 3) << 2;
    const int brow = tid >> 4;           // 0..15
    const int bcol = (tid & 15) << 3;    // 0..120

    float accf[8][8];
#pragma unroll
    for (int i = 0; i < 8; i++)
#pragma unroll
        for (int j = 0; j < 8; j++) accf[i][j] = 0.f;

    const float* Ap  = qp + (size_t)(b * S_ + bm + lrow) * JD + lcol;
    const float* Ap2 = Ap + (size_t)64 * JD;

    for (int k0 = 0; k0 < JD; k0 += 16) {
        float4 a0 = *(const float4*)(Ap  + k0);
        float4 a1 = *(const float4*)(Ap2 + k0);
        int hh = (k0 + lcol) >> 6;
        float sc0 = rscale[(size_t)(b * 16 + hh) * S_ + bm + lrow];
        float sc1 = rscale[(size_t)(b * 16 + hh) * S_ + bm + lrow + 64];
        float4 b0 = *(const float4*)&kvo[((size_t)b * 1024 + k0 + brow) * Hd + bn + bcol];
        float4 b1 = *(const float4*)&kvo[((size_t)b * 1024 + k0 + brow) * Hd + bn + bcol + 4];
        __syncthreads();
        As[lcol + 0][lrow] = a0.x * sc0; As[lcol + 1][lrow] = a0.y * sc0;
        As[lcol + 2][lrow] = a0.z * sc0; As[lcol + 3][lrow] = a0.w * sc0;
        As[lcol + 0][lrow + 64] = a1.x * sc1; As[lcol + 1][lrow + 64] = a1.y * sc1;
        As[lcol + 2][lrow + 64] = a1.z * sc1; As[lcol + 3][lrow + 64] = a1.w * sc1;
        *(float4*)&Bs[brow][bcol]     = b0;
        *(float4*)&Bs[brow][bcol + 4] = b1;
        __syncthreads();
#pragma unroll
        for (int kk = 0; kk < 16; kk++) {
            const float4 av0 = *(const float4*)&As[kk][ty * 4];
            const float4 av1 = *(const float4*)&As[kk][ty * 4 + 64];
            const float4 bv0 = *(const float4*)&Bs[kk][tx * 4];
            const float4 bv1 = *(const float4*)&Bs[kk][tx * 4 + 64];
            const float a_[8] = {av0.x, av0.y, av0.z, av0.w, av1.x, av1.y, av1.z, av1.w};
            const float b_[8] = {bv0.x, bv0.y, bv0.z, bv0.w, bv1.x, bv1.y, bv1.z, bv1.w};
#pragma unroll
            for (int i = 0; i < 8; i++)
#pragma unroll
                for (int j = 0; j < 8; j++)
                    accf[i][j] += a_[i] * b_[j];
        }
    }

#pragma unroll
    for (int i = 0; i < 8; i++) {
        int row = b * S_ + bm + (i >> 2) * 64 + ty * 4 + (i & 3);
#pragma unroll
        for (int jh = 0; jh < 2; jh++) {
            int col = bn + jh * 64 + tx * 4;
            float4 bv4 = *(const float4*)&bo[col];
            float4 r;
            r.x = accf[i][jh * 4 + 0] + bv4.x;
            r.y = accf[i][jh * 4 + 1] + bv4.y;
            r.z = accf[i][jh * 4 + 2] + bv4.z;
            r.w = accf[i][jh * 4 + 3] + bv4.w;
            *(float4*)&out[(size_t)row * Hd + col] = r;
        }
    }
}

// ---------------------------------------------------------------------------
extern "C" void kernel_launch(void* const* d_in, const int* in_sizes, int n_in,
                              void* d_out, int out_size, void* d_ws, size_t ws_size,
                              hipStream_t stream)
{
    const float* query = (const float*)d_in[0];
    const float* key   = (const float*)d_in[1];
    const float* value = (const float*)d_in[2];
    const float* amask = (const float*)d_in[3];
    const float* Wq  = (const float*)d_in[4];
    const float* bq  = (const float*)d_in[5];
    const float* Wk  = (const float*)d_in[6];
    const float* bk  = (const float*)d_in[7];
    const float* Wv  = (const float*)d_in[8];
    const float* bv  = (const float*)d_in[9];
    const float* Wqf = (const float*)d_in[10];
    const float* Wkf = (const float*)d_in[11];
    const float* Wo  = (const float*)d_in[12];
    const float* bo  = (const float*)d_in[13];
    float* out = (float*)d_out;

    float* ws = (float*)d_ws;
    float* qp   = ws;                                  // 16384*1024
    float* kp   = qp   + (size_t)MTOT * JD;            // 16384*1024
    float* vv   = kp   + (size_t)MTOT * JD;            // 16384*2048
    float* Wcq  = vv   + (size_t)MTOT * Hd;            // 1024*2048
    float* Wck  = Wcq  + (size_t)JD * Hd;              // 1024*2048
    float* bcq  = Wck  + (size_t)JD * Hd;              // 1024
    float* bck  = bcq  + 1024;                         // 1024
    float* kvp  = bck  + 1024;                         // 8*64*8192
    float* ksp  = kvp  + (size_t)8 * 64 * 8192;        // 8*64*64
    float* kv   = ksp  + (size_t)8 * 64 * 64;          // 64*8192
    float* ksum = kv   + (size_t)64 * 8192;            // 64*64
    float* kvo  = ksum + (size_t)64 * 64;              // 4*1024*2048
    float* rs   = kvo  + (size_t)4 * 1024 * 2048;      // 64*4096

    combine_w_kernel<<<dim3(8, 16, 2), 256, 0, stream>>>(Wq, Wqf, bq, Wk, Wkf, bk,
                                                         Wcq, bcq, Wck, bck);
    gemm_nt<1><<<dim3(8, 128), 256, 0, stream>>>(query, Wcq, bcq, nullptr, qp, JD, Hd);
    gemm_nt<2><<<dim3(8, 128), 256, 0, stream>>>(key,   Wck, bck, amask,  kp, JD, Hd);
    gemm_nt<0><<<dim3(16, 128), 256, 0, stream>>>(value, Wv,  bv,  nullptr, vv, Hd, Hd);
    kv_partial_kernel<<<dim3(8, 64), 256, 0, stream>>>(kp, vv, kvp, ksp);
    kv_reduce_kernel<<<64, 256, 0, stream>>>(kvp, ksp, kv, ksum);
    rscale_kernel<<<1024, 256, 0, stream>>>(qp, ksum, rs);
    kvo_kernel<<<dim3(8, 64), 256, 0, stream>>>(kv, Wo, kvo);
    gemm_out_kernel<<<dim3(16, 32, 4), 256, 0, stream>>>(qp, rs, kvo, bo, out);
}

// Round 3
// 1782.102 us; speedup vs baseline: 2.4584x; 2.4584x over previous
//
#include <hip/hip_runtime.h>

#define B_   4
#define S_   4096
#define Hd   2048
#define NHh  16
#define HDd  128
#define FDd  64
#define MTOT (B_*S_)      // 16384
#define JD   (NHh*FDd)    // 1024

typedef __attribute__((ext_vector_type(8))) short short8;
typedef __attribute__((ext_vector_type(4))) float f32x4;

#define SWZ(m) (((m) >> 1) & 3)

// ---------------------------------------------------------------------------
// fp32 -> bf16 hi (truncate) + bf16 lo (RNE of remainder).  hi+lo ~ 17 bits.
// ---------------------------------------------------------------------------
__device__ __forceinline__ void split2(float x, ushort& h, ushort& l) {
    unsigned u = __builtin_bit_cast(unsigned, x);
    h = (ushort)(u >> 16);
    float hf = __builtin_bit_cast(float, u & 0xFFFF0000u);
    float r = x - hf;
    unsigned v = __builtin_bit_cast(unsigned, r);
    unsigned rnd = v + 0x7FFFu + ((v >> 16) & 1u);
    l = (ushort)(rnd >> 16);
}

__device__ __forceinline__ void gload_lds16(const void* g, void* l) {
    __builtin_amdgcn_global_load_lds(
        (__attribute__((address_space(1))) void*)(g),
        (__attribute__((address_space(3))) void*)(l), 16, 0, 0);
}

// ---------------------------------------------------------------------------
// split_kernel: x[n] fp32 -> hi/lo bf16 planes (float4-vectorized)
// ---------------------------------------------------------------------------
__global__ __launch_bounds__(256) void split_kernel(
    const float* __restrict__ x, ushort* __restrict__ hi, ushort* __restrict__ lo, int n4)
{
    int i = blockIdx.x * 256 + threadIdx.x;
    if (i >= n4) return;
    float4 v = ((const float4*)x)[i];
    ushort4 H, L;
    split2(v.x, H.x, L.x);
    split2(v.y, H.y, L.y);
    split2(v.z, H.z, L.z);
    split2(v.w, H.w, L.w);
    ((ushort4*)hi)[i] = H;
    ((ushort4*)lo)[i] = L;
}

// ---------------------------------------------------------------------------
// scale_split: (qp[m,j] * rscale[b, j/64, n]) -> split bf16   (for final GEMM A)
// qp: [16384][1024], rs: [64][4096]
// ---------------------------------------------------------------------------
__global__ __launch_bounds__(256) void scale_split_kernel(
    const float* __restrict__ qp, const float* __restrict__ rs,
    ushort* __restrict__ hi, ushort* __restrict__ lo)
{
    int i = blockIdx.x * 256 + threadIdx.x;   // float4 index, 4,194,304 total
    int m = i >> 8;                           // row
    int c4 = i & 255;
    int hh = c4 >> 4;                         // head = (c4*4)/64
    int b = m >> 12, n = m & 4095;
    float s = rs[(size_t)(b * 16 + hh) * S_ + n];
    float4 v = ((const float4*)qp)[i];
    ushort4 H, L;
    split2(v.x * s, H.x, L.x);
    split2(v.y * s, H.y, L.y);
    split2(v.z * s, H.z, L.z);
    split2(v.w * s, H.w, L.w);
    ((ushort4*)hi)[i] = H;
    ((ushort4*)lo)[i] = L;
}

// ---------------------------------------------------------------------------
// Combine weights: Wc[h*64+f, i] = sum_d Wf[f,d] * W[h*128+d, i]  (split bf16 out)
//                  bc[h*64+f]    = sum_d  b[h*128+d] * Wf[f,d]    (fp32)
// grid: (8 i-chunks of 256, 16 h, 2 which)   block: 256
// ---------------------------------------------------------------------------
__global__ __launch_bounds__(256) void combine_w_kernel(
    const float* __restrict__ Wq, const float* __restrict__ Wqf, const float* __restrict__ bq,
    const float* __restrict__ Wk, const float* __restrict__ Wkf, const float* __restrict__ bk,
    ushort* __restrict__ Wcq_hi, ushort* __restrict__ Wcq_lo, float* __restrict__ bcq,
    ushort* __restrict__ Wck_hi, ushort* __restrict__ Wck_lo, float* __restrict__ bck)
{
    const int tid = threadIdx.x;
    const int h = blockIdx.y;
    const int which = blockIdx.z;
    const float* W  = which ? Wk  : Wq;
    const float* Wf = which ? Wkf : Wqf;
    const float* bb = which ? bk  : bq;
    ushort* Wh = which ? Wck_hi : Wcq_hi;
    ushort* Wl = which ? Wck_lo : Wcq_lo;
    float* bc = which ? bck : bcq;

    __shared__ float wfT[128 * 64];   // [d][f]
    for (int idx = tid; idx < 64 * 128; idx += 256) {
        int f = idx >> 7, d = idx & 127;
        wfT[d * 64 + f] = Wf[idx];
    }
    __syncthreads();

    const int i = blockIdx.x * 256 + tid;
    float acc[64];
#pragma unroll
    for (int f = 0; f < 64; f++) acc[f] = 0.f;

    for (int d = 0; d < 128; d++) {
        float w = W[(size_t)(h * 128 + d) * Hd + i];
        const float* wr = &wfT[d * 64];
#pragma unroll
        for (int f4 = 0; f4 < 16; f4++) {
            float4 ww = *(const float4*)&wr[f4 * 4];
            acc[f4 * 4 + 0] += ww.x * w;
            acc[f4 * 4 + 1] += ww.y * w;
            acc[f4 * 4 + 2] += ww.z * w;
            acc[f4 * 4 + 3] += ww.w * w;
        }
    }
#pragma unroll
    for (int f = 0; f < 64; f++) {
        ushort sh, sl;
        split2(acc[f], sh, sl);
        size_t idx = (size_t)(h * 64 + f) * Hd + i;
        Wh[idx] = sh;
        Wl[idx] = sl;
    }

    if (blockIdx.x == 0 && tid < 64) {
        float s = 0.f;
        for (int d = 0; d < 128; d++) s += bb[h * 128 + d] * wfT[d * 64 + tid];
        bc[h * 64 + tid] = s;
    }
}

// ---------------------------------------------------------------------------
// Split-bf16 MFMA GEMM (NT): C[m,n] = epi( sum_k A[m,k]*B[n,k] + bias[n] )
//   A ~ Ahi+Alo, B ~ Bhi+Blo;  acc += Ah*Bh + Ah*Bl + Al*Bh   (3 MFMAs)
// 128x128 tile, BK=32, 256 threads (4 waves, 2x2 of 64x64), mfma_16x16x32.
// XOR-swizzled LDS chunk layout -> conflict-free ds_read_b128.
// blockIdx.z batches B (stride N*K) and rows (stride mPerZ).
// MODE 0: +bias      MODE 1: relu(+bias)      MODE 2: relu(+bias)*mask[row]
// ---------------------------------------------------------------------------
template <int MODE>
__global__ __launch_bounds__(256) void gemm_mfma(
    const ushort* __restrict__ Ahi, const ushort* __restrict__ Alo,
    const ushort* __restrict__ Bhi, const ushort* __restrict__ Blo,
    const float* __restrict__ bias, const float* __restrict__ mask,
    float* __restrict__ C, int N, int K, int mPerZ)
{
    __shared__ ushort Ah[128 * 32];
    __shared__ ushort Al[128 * 32];
    __shared__ ushort Bh[128 * 32];
    __shared__ ushort Bl[128 * 32];

    const int tid  = threadIdx.x;
    const int wave = tid >> 6;
    const int lane = tid & 63;
    const size_t rowBase = (size_t)blockIdx.z * mPerZ + (size_t)blockIdx.y * 128;
    const int    colBase = blockIdx.x * 128;
    const ushort* Bhz = Bhi + (size_t)blockIdx.z * N * K;
    const ushort* Blz = Blo + (size_t)blockIdx.z * N * K;

    const int wm = (wave >> 1) * 64;   // wave tile row offset in 128
    const int wn = (wave & 1) * 64;    // wave tile col offset in 128
    const int fm   = lane & 15;
    const int quad = lane >> 4;

    f32x4 acc[4][4];
#pragma unroll
    for (int i = 0; i < 4; i++)
#pragma unroll
        for (int j = 0; j < 4; j++) acc[i][j] = (f32x4){0.f, 0.f, 0.f, 0.f};

    // staging lane geometry
    const int srow = lane >> 2;   // 0..15 row within a 16-row issue
    const int qs   = lane & 3;    // LDS chunk slot

    for (int k0 = 0; k0 < K; k0 += 32) {
        __syncthreads();
#pragma unroll
        for (int i = 0; i < 2; i++) {
            const int ml = wave * 32 + i * 16 + srow;   // tile-local row 0..127
            const int q  = qs ^ SWZ(ml);                 // global k-chunk for this slot
            const size_t ga = (rowBase + ml) * (size_t)K + k0 + q * 8;
            const size_t gb = (size_t)(colBase + ml) * K + k0 + q * 8;
            const int ldsb = (wave * 32 + i * 16) * 32;  // uniform per wave+issue (elems)
            gload_lds16(Ahi + ga, &Ah[ldsb]);
            gload_lds16(Alo + ga, &Al[ldsb]);
            gload_lds16(Bhz + gb, &Bh[ldsb]);
            gload_lds16(Blz + gb, &Bl[ldsb]);
        }
        __syncthreads();

        short8 a_h[4], a_l[4], b_h[4], b_l[4];
#pragma unroll
        for (int t = 0; t < 4; t++) {
            const int m  = wm + t * 16 + fm;
            const int oa = m * 32 + ((quad ^ SWZ(m)) * 8);
            a_h[t] = *(const short8*)&Ah[oa];
            a_l[t] = *(const short8*)&Al[oa];
            const int n  = wn + t * 16 + fm;
            const int ob = n * 32 + ((quad ^ SWZ(n)) * 8);
            b_h[t] = *(const short8*)&Bh[ob];
            b_l[t] = *(const short8*)&Bl[ob];
        }
#pragma unroll
        for (int mi = 0; mi < 4; mi++)
#pragma unroll
            for (int ni = 0; ni < 4; ni++) {
                acc[mi][ni] = __builtin_amdgcn_mfma_f32_16x16x32_bf16(a_h[mi], b_h[ni], acc[mi][ni], 0, 0, 0);
                acc[mi][ni] = __builtin_amdgcn_mfma_f32_16x16x32_bf16(a_h[mi], b_l[ni], acc[mi][ni], 0, 0, 0);
                acc[mi][ni] = __builtin_amdgcn_mfma_f32_16x16x32_bf16(a_l[mi], b_h[ni], acc[mi][ni], 0, 0, 0);
            }
    }

    // epilogue: C/D layout col=lane&15, row=quad*4+reg
    float bias_v[4];
#pragma unroll
    for (int ni = 0; ni < 4; ni++) bias_v[ni] = bias[colBase + wn + ni * 16 + fm];

#pragma unroll
    for (int mi = 0; mi < 4; mi++) {
#pragma unroll
        for (int r = 0; r < 4; r++) {
            const size_t grow = rowBase + wm + mi * 16 + quad * 4 + r;
            float mval = 1.f;
            if (MODE == 2) mval = mask[grow];
#pragma unroll
            for (int ni = 0; ni < 4; ni++) {
                float val = acc[mi][ni][r] + bias_v[ni];
                if (MODE >= 1) val = val > 0.f ? val : 0.f;
                if (MODE == 2) val *= mval;
                C[grow * N + colBase + wn + ni * 16 + fm] = val;
            }
        }
    }
}

// ---------------------------------------------------------------------------
// kv partial: per (b,h,chunk) accumulate kv[f,e] += k'[n,f]*v[n,e], ksum[f]
// ---------------------------------------------------------------------------
__global__ __launch_bounds__(256) void kv_partial_kernel(
    const float* __restrict__ kp, const float* __restrict__ v,
    float* __restrict__ kv_part, float* __restrict__ ksum_part)
{
    const int tid = threadIdx.x;
    const int bh = blockIdx.y;
    const int b = bh >> 4, h = bh & 15;
    const int c = blockIdx.x;
    __shared__ float Ks[8][64];
    __shared__ float Vs[8][128];
    const int fi = tid & 15;
    const int eg = tid >> 4;
    float acc[4][8];
#pragma unroll
    for (int i = 0; i < 4; i++)
#pragma unroll
        for (int j = 0; j < 8; j++) acc[i][j] = 0.f;
    float ksacc = 0.f;

    for (int n0 = c * 512; n0 < c * 512 + 512; n0 += 8) {
        __syncthreads();
        if (tid < 128) {
            int nn = tid >> 4, fc = (tid & 15) << 2;
            *(float4*)&Ks[nn][fc] = *(const float4*)&kp[(size_t)(b * S_ + n0 + nn) * JD + h * 64 + fc];
        }
        {
            int nn = tid >> 5, ec = (tid & 31) << 2;
            *(float4*)&Vs[nn][ec] = *(const float4*)&v[(size_t)(b * S_ + n0 + nn) * Hd + h * 128 + ec];
        }
        __syncthreads();
#pragma unroll
        for (int nn = 0; nn < 8; nn++) {
            float4 kk = *(const float4*)&Ks[nn][fi * 4];
            float4 v0 = *(const float4*)&Vs[nn][eg * 8];
            float4 v1 = *(const float4*)&Vs[nn][eg * 8 + 4];
            const float kf[4] = {kk.x, kk.y, kk.z, kk.w};
            const float vf[8] = {v0.x, v0.y, v0.z, v0.w, v1.x, v1.y, v1.z, v1.w};
#pragma unroll
            for (int i = 0; i < 4; i++)
#pragma unroll
                for (int j = 0; j < 8; j++) acc[i][j] += kf[i] * vf[j];
            if (tid < 64) ksacc += Ks[nn][tid];
        }
    }
    size_t base = ((size_t)c * 64 + bh) * 8192;
#pragma unroll
    for (int i = 0; i < 4; i++) {
        int f = fi * 4 + i;
        float4 r0 = {acc[i][0], acc[i][1], acc[i][2], acc[i][3]};
        float4 r1 = {acc[i][4], acc[i][5], acc[i][6], acc[i][7]};
        *(float4*)&kv_part[base + (size_t)f * 128 + eg * 8]     = r0;
        *(float4*)&kv_part[base + (size_t)f * 128 + eg * 8 + 4] = r1;
    }
    if (tid < 64) ksum_part[((size_t)c * 64 + bh) * 64 + tid] = ksacc;
}

__global__ __launch_bounds__(256) void kv_reduce_kernel(
    const float* __restrict__ kv_part, const float* __restrict__ ksum_part,
    float* __restrict__ kv, float* __restrict__ ksum)
{
    const int bh = blockIdx.x, tid = threadIdx.x;
    for (int idx = tid; idx < 8192; idx += 256) {
        float s = 0.f;
#pragma unroll
        for (int c = 0; c < 8; c++) s += kv_part[((size_t)c * 64 + bh) * 8192 + idx];
        kv[(size_t)bh * 8192 + idx] = s;
    }
    if (tid < 64) {
        float s = 0.f;
#pragma unroll
        for (int c = 0; c < 8; c++) s += ksum_part[((size_t)c * 64 + bh) * 64 + tid];
        ksum[bh * 64 + tid] = s;
    }
}

// ---------------------------------------------------------------------------
// rscale[b,h,n] = 1 / (sum_f q'[m, h*64+f]*ksum[b,h,f] + 1e-8)
// ---------------------------------------------------------------------------
__global__ __launch_bounds__(256) void rscale_kernel(
    const float* __restrict__ qp, const float* __restrict__ ksum, float* __restrict__ rscale)
{
    int idx = blockIdx.x * 256 + threadIdx.x;   // 0..262143
    int m = idx >> 4;
    int h = idx & 15;
    int b = m >> 12;
    int n = m & 4095;
    const float* q  = qp + (size_t)m * JD + h * 64;
    const float* ks = ksum + (b * 16 + h) * 64;
    float s = 0.f;
#pragma unroll
    for (int f4 = 0; f4 < 16; f4++) {
        float4 qa = *(const float4*)&q[f4 * 4];
        float4 ka = *(const float4*)&ks[f4 * 4];
        s += qa.x * ka.x + qa.y * ka.y + qa.z * ka.z + qa.w * ka.w;
    }
    rscale[(size_t)(b * 16 + h) * S_ + n] = 1.f / (s + 1e-8f);
}

// ---------------------------------------------------------------------------
// kvoT[b, o, h*64+f] = sum_e kv[b,h,f,e] * Wo[o, h*128+e]   (split bf16 out)
// grid: (8 o-chunks of 256, 64 bh)  block 256
// ---------------------------------------------------------------------------
__global__ __launch_bounds__(256) void kvo_kernel(
    const float* __restrict__ kv, const float* __restrict__ Wo,
    ushort* __restrict__ kvoT_hi, ushort* __restrict__ kvoT_lo)
{
    const int tid = threadIdx.x;
    const int bh = blockIdx.y;
    const int b = bh >> 4, h = bh & 15;
    const int o0 = blockIdx.x * 256;
    __shared__ float kvs[8192];
    for (int idx = tid * 4; idx < 8192; idx += 1024)
        *(float4*)&kvs[idx] = *(const float4*)&kv[(size_t)bh * 8192 + idx];
    __syncthreads();

    const int ol = tid & 63;
    const int fg = tid >> 6;   // 0..3 -> f = fg*16..+15
    float acc[4][16];
#pragma unroll
    for (int i = 0; i < 4; i++)
#pragma unroll
        for (int j = 0; j < 16; j++) acc[i][j] = 0.f;

    for (int e4 = 0; e4 < 32; e4++) {
        float4 wv[4];
#pragma unroll
        for (int oo = 0; oo < 4; oo++) {
            int o = o0 + oo * 64 + ol;
            wv[oo] = *(const float4*)&Wo[(size_t)o * Hd + h * 128 + e4 * 4];
        }
#pragma unroll
        for (int ff = 0; ff < 16; ff++) {
            float4 kk = *(const float4*)&kvs[(fg * 16 + ff) * 128 + e4 * 4];
#pragma unroll
            for (int oo = 0; oo < 4; oo++)
                acc[oo][ff] += kk.x * wv[oo].x + kk.y * wv[oo].y + kk.z * wv[oo].z + kk.w * wv[oo].w;
        }
    }
#pragma unroll
    for (int ff = 0; ff < 16; ff++) {
        int f = fg * 16 + ff;
#pragma unroll
        for (int oo = 0; oo < 4; oo++) {
            int o = o0 + oo * 64 + ol;
            ushort sh, sl;
            split2(acc[oo][ff], sh, sl);
            size_t idx = ((size_t)b * 2048 + o) * 1024 + h * 64 + f;
            kvoT_hi[idx] = sh;
            kvoT_lo[idx] = sl;
        }
    }
}

// ---------------------------------------------------------------------------
// Workspace plan (total 338.2 MiB, <= round-1's proven 339.1 MiB watermark).
// Liveness-based aliasing; single-stream ordering provides the dependencies.
//   R1 (128 MiB): input split planes (V,K,Q in turn) -> kvp partials -> kvoT planes
//   R2 (128 MiB): vv fp32 -> qp fp32 (first half)
//   R3 ( 64 MiB): Wv split planes -> kp fp32 -> scaled-q split planes
//   R4 ( 16 MiB): Wcq/Wck split planes; rs aliases dead Wck_hi
//   R5 (~2.2 MiB): kv, ksp, ksum, bcq, bck
// ---------------------------------------------------------------------------
extern "C" void kernel_launch(void* const* d_in, const int* in_sizes, int n_in,
                              void* d_out, int out_size, void* d_ws, size_t ws_size,
                              hipStream_t stream)
{
    const float* query = (const float*)d_in[0];
    const float* key   = (const float*)d_in[1];
    const float* value = (const float*)d_in[2];
    const float* amask = (const float*)d_in[3];
    const float* Wq  = (const float*)d_in[4];
    const float* bq  = (const float*)d_in[5];
    const float* Wk  = (const float*)d_in[6];
    const float* bk  = (const float*)d_in[7];
    const float* Wv  = (const float*)d_in[8];
    const float* bv  = (const float*)d_in[9];
    const float* Wqf = (const float*)d_in[10];
    const float* Wkf = (const float*)d_in[11];
    const float* Wo  = (const float*)d_in[12];
    const float* bo  = (const float*)d_in[13];
    float* out = (float*)d_out;

    const size_t MiB = 1024 * 1024;
    char* base = (char*)d_ws;
    char* R1 = base;                 // 128 MiB
    char* R2 = R1 + 128 * MiB;       // 128 MiB
    char* R3 = R2 + 128 * MiB;       //  64 MiB
    char* R4 = R3 + 64 * MiB;        //  16 MiB
    char* R5 = R4 + 16 * MiB;        //  ~2.2 MiB

    // R1 occupants
    ushort* in_hi   = (ushort*)R1;                  // 64 MiB
    ushort* in_lo   = (ushort*)(R1 + 64 * MiB);     // 64 MiB
    float*  kvp     = (float*) R1;                  // 16 MiB   (after gemm_k)
    ushort* kvoT_hi = (ushort*)R1;                  // 16 MiB   (after gemm_q)
    ushort* kvoT_lo = (ushort*)(R1 + 16 * MiB);     // 16 MiB
    // R2 occupants
    float*  vv      = (float*) R2;                  // 128 MiB
    float*  qp      = (float*) R2;                  // 64 MiB   (after kv_partial)
    // R3 occupants
    ushort* Wv_hi   = (ushort*)R3;                  // 8 MiB
    ushort* Wv_lo   = (ushort*)(R3 + 8 * MiB);      // 8 MiB
    float*  kp      = (float*) R3;                  // 64 MiB   (after gemm_v)
    ushort* qf_hi   = (ushort*)R3;                  // 32 MiB   (after kv_partial)
    ushort* qf_lo   = (ushort*)(R3 + 32 * MiB);     // 32 MiB
    // R4 occupants
    ushort* Wcq_hi  = (ushort*)R4;                  // 4 MiB
    ushort* Wcq_lo  = (ushort*)(R4 + 4 * MiB);      // 4 MiB
    ushort* Wck_hi  = (ushort*)(R4 + 8 * MiB);      // 4 MiB
    ushort* Wck_lo  = (ushort*)(R4 + 12 * MiB);     // 4 MiB
    float*  rs      = (float*) (R4 + 8 * MiB);      // 1 MiB    (after gemm_k)
    // R5 occupants
    float*  kv      = (float*) R5;                  // 2 MiB
    float*  ksp     = (float*) (R5 + 2 * MiB);      // 128 KiB
    float*  ksum    = (float*) (R5 + 2 * MiB + 128 * 1024);
    float*  bcq     = (float*) (R5 + 2 * MiB + 160 * 1024);
    float*  bck     = (float*) (R5 + 2 * MiB + 168 * 1024);

    // ---- weights ----
    combine_w_kernel<<<dim3(8, 16, 2), 256, 0, stream>>>(Wq, Wqf, bq, Wk, Wkf, bk,
                                                         Wcq_hi, Wcq_lo, bcq, Wck_hi, Wck_lo, bck);
    split_kernel<<<(Hd * Hd / 4 + 255) / 256, 256, 0, stream>>>(Wv, Wv_hi, Wv_lo, Hd * Hd / 4);

    // ---- v = value @ Wv^T + bv ----
    split_kernel<<<(MTOT * Hd / 4 + 255) / 256, 256, 0, stream>>>(value, in_hi, in_lo, MTOT * Hd / 4);
    gemm_mfma<0><<<dim3(16, 128, 1), 256, 0, stream>>>(in_hi, in_lo, Wv_hi, Wv_lo, bv, nullptr,
                                                       vv, Hd, Hd, 0);

    // ---- k' = relu(key @ Wck^T + bck) * mask ----  (kp overwrites dead Wv splits)
    split_kernel<<<(MTOT * Hd / 4 + 255) / 256, 256, 0, stream>>>(key, in_hi, in_lo, MTOT * Hd / 4);
    gemm_mfma<2><<<dim3(8, 128, 1), 256, 0, stream>>>(in_hi, in_lo, Wck_hi, Wck_lo, bck, amask,
                                                      kp, JD, Hd, 0);

    // ---- kv aggregation (kvp overwrites dead key split in R1) ----
    kv_partial_kernel<<<dim3(8, 64), 256, 0, stream>>>(kp, vv, kvp, ksp);
    kv_reduce_kernel<<<64, 256, 0, stream>>>(kvp, ksp, kv, ksum);

    // ---- q' = relu(query @ Wcq^T + bcq) ----  (qp overwrites dead vv)
    split_kernel<<<(MTOT * Hd / 4 + 255) / 256, 256, 0, stream>>>(query, in_hi, in_lo, MTOT * Hd / 4);
    gemm_mfma<1><<<dim3(8, 128, 1), 256, 0, stream>>>(in_hi, in_lo, Wcq_hi, Wcq_lo, bcq, nullptr,
                                                      qp, JD, Hd, 0);

    // ---- normalization scale ----  (rs overwrites dead Wck_hi)
    rscale_kernel<<<1024, 256, 0, stream>>>(qp, ksum, rs);

    // ---- A = q'*rscale (split, into dead kp region); B = kvoT (into dead query split) ----
    scale_split_kernel<<<16384, 256, 0, stream>>>(qp, rs, qf_hi, qf_lo);
    kvo_kernel<<<dim3(8, 64), 256, 0, stream>>>(kv, Wo, kvoT_hi, kvoT_lo);

    // ---- out = A @ kvoT^T + bo   (batched over b) ----
    gemm_mfma<0><<<dim3(16, 32, 4), 256, 0, stream>>>(qf_hi, qf_lo, kvoT_hi, kvoT_lo, bo, nullptr,
                                                      out, Hd, JD, S_);
}